// Round 3
// baseline (236.678 us; speedup 1.0000x reference)
//
#include <hip/hip_runtime.h>

// out[m,k] = D*(w-1)*rowsum(t[m]) broadcast over k (K = D = 2048).
//
// R1-R8: all fused variants 71-82 us. R9 (pure-read kernel + pure-write
// kernel): harness -2 us. R10 (one kernel, whole grid co-resident, phased
// read-then-write): +3 us. Three structurally disjoint kernels within the
// fill-jitter noise band => structure is NOT the bottleneck.
//
// R11 theory: the common factor is NT *loads*. Input = 134 MB < 256 MiB
// Infinity Cache, uploaded once; per-iter fills re-poison the OUTPUT, not
// the input => input can stay L3-warm across graph replays. NT load hints
// (no-reuse / cache-bypass) forfeit that, forcing full-HBM reads every
// iteration. Change EXACTLY one thing vs R10: plain cached loads for the
// input. NT stores stay (output never re-read; NT writes avoid evicting
// the input's L3 residency).
// Predict: read phase served from L3, kernel ~60 -> ~30-38 us, harness
// 222 -> ~195-205. If unchanged: reads were already at HBM floor =>
// kernel is at the memory roofline (residual = fixed harness fills).

#define M_ROWS 16384
#define D_COLS 2048
#define F4_PER_ROW (D_COLS / 4)   // 512
#define WAVES_PER_BLOCK 4
#define BLOCK_SIZE (WAVES_PER_BLOCK * 64)
#define ROWS_PER_WAVE 8
#define GRID_BLOCKS (M_ROWS / (WAVES_PER_BLOCK * ROWS_PER_WAVE))  // 512

typedef float vf4 __attribute__((ext_vector_type(4)));

__global__ __launch_bounds__(BLOCK_SIZE)
void perm_equiv_cached(const float* __restrict__ t,
                       const float* __restrict__ w,
                       float* __restrict__ out) {
    const int lane  = threadIdx.x & 63;
    const int gwave = blockIdx.x * WAVES_PER_BLOCK + (threadIdx.x >> 6);
    const size_t row0 = (size_t)gwave * ROWS_PER_WAVE;   // 8 contiguous rows

    const float scale = (float)D_COLS * (w[0] - 1.0f);

    const vf4* base = reinterpret_cast<const vf4*>(t) + row0 * F4_PER_ROW;

    vf4 buf0[8], buf1[8];          // 2-row double buffer
    float sums[ROWS_PER_WAVE];     // fully unrolled -> registers

    // ---- READ phase: plain cached loads (L3 can serve the warm input) ----
    #pragma unroll
    for (int j = 0; j < 8; ++j)
        buf0[j] = base[j * 64 + lane];

    #pragma unroll
    for (int r = 0; r < ROWS_PER_WAVE; ++r) {
        if (r + 1 < ROWS_PER_WAVE) {
            const vf4* p = base + (size_t)(r + 1) * F4_PER_ROW;
            if (r & 1) {
                #pragma unroll
                for (int j = 0; j < 8; ++j)
                    buf0[j] = p[j * 64 + lane];
            } else {
                #pragma unroll
                for (int j = 0; j < 8; ++j)
                    buf1[j] = p[j * 64 + lane];
            }
        }

        float s = 0.0f;
        if (r & 1) {
            #pragma unroll
            for (int j = 0; j < 8; ++j)
                s += (buf1[j].x + buf1[j].y) + (buf1[j].z + buf1[j].w);
        } else {
            #pragma unroll
            for (int j = 0; j < 8; ++j)
                s += (buf0[j].x + buf0[j].y) + (buf0[j].z + buf0[j].w);
        }

        // wave-64 butterfly: every lane ends with the full row sum.
        #pragma unroll
        for (int m = 32; m > 0; m >>= 1)
            s += __shfl_xor(s, m, 64);

        sums[r] = scale * s;
    }

    __syncthreads();

    // ---- WRITE phase: NT stores (never re-read; don't evict input's L3) ----
    vf4* obase = reinterpret_cast<vf4*>(out) + row0 * F4_PER_ROW;
    #pragma unroll
    for (int r = 0; r < ROWS_PER_WAVE; ++r) {
        vf4 v4;
        v4.x = sums[r]; v4.y = sums[r]; v4.z = sums[r]; v4.w = sums[r];
        vf4* orow = obase + (size_t)r * F4_PER_ROW;
        #pragma unroll
        for (int j = 0; j < 8; ++j)
            __builtin_nontemporal_store(v4, orow + j * 64 + lane);
    }
}

extern "C" void kernel_launch(void* const* d_in, const int* in_sizes, int n_in,
                              void* d_out, int out_size, void* d_ws, size_t ws_size,
                              hipStream_t stream) {
    const float* t = (const float*)d_in[0];
    const float* w = (const float*)d_in[1];
    float* out = (float*)d_out;
    perm_equiv_cached<<<GRID_BLOCKS, BLOCK_SIZE, 0, stream>>>(t, w, out);
}

// Round 4
// 223.791 us; speedup vs baseline: 1.0576x; 1.0576x over previous
//
#include <hip/hip_runtime.h>

// out[m,k] = D*(w-1)*rowsum(t[m]) broadcast over k (K = D = 2048).
//
// Evidence ledger:
//  R0-R8 (prior session): all fused NT/NT variants, kernel ~61-82 us.
//  R9  NT/NT split read-kernel + write-kernel: harness 219.3 (best).
//  R10 NT/NT single kernel, phased:            harness 222.9 (~67 us kernel).
//  R11 cached-loads/NT-stores (one flip vs R10): kernel 80.6 us DIRECT,
//      FETCH 67 MB (half the input L3-hit!) yet SLOWER => cache-path reads
//      lose to NT streaming; cached loads rejected. Harness copyBuffer
//      corroborates: 79.4 us / 2.5 TB/s for the same input.
//  => Every ~60-67 us variant shares NT STORES, never A/B'd. The 6.7 TB/s
//     write proof (fillBuffer) uses PLAIN stores. Hypothesis: NT stores
//     bypass L2 write-combining / L3 absorption and cap ~4.5 TB/s, pinning
//     every structure to the same ~60+ us.
//
// R12: single flip vs R10 — NT loads (kept), stores now PLAIN cached.
// Predict: kernel 67 -> ~45-55 us (WRITE_SIZE may dip under 131072 KB as
// dirty lines rest in L3 at retire), harness -> ~203-212. If unchanged,
// stores exonerated => practical mixed-stream roofline reached.

#define M_ROWS 16384
#define D_COLS 2048
#define F4_PER_ROW (D_COLS / 4)   // 512
#define WAVES_PER_BLOCK 4
#define BLOCK_SIZE (WAVES_PER_BLOCK * 64)
#define ROWS_PER_WAVE 8
#define GRID_BLOCKS (M_ROWS / (WAVES_PER_BLOCK * ROWS_PER_WAVE))  // 512

typedef float vf4 __attribute__((ext_vector_type(4)));

__global__ __launch_bounds__(BLOCK_SIZE)
void perm_equiv_ntld_cst(const float* __restrict__ t,
                         const float* __restrict__ w,
                         float* __restrict__ out) {
    const int lane  = threadIdx.x & 63;
    const int gwave = blockIdx.x * WAVES_PER_BLOCK + (threadIdx.x >> 6);
    const size_t row0 = (size_t)gwave * ROWS_PER_WAVE;   // 8 contiguous rows

    const float scale = (float)D_COLS * (w[0] - 1.0f);

    const vf4* base = reinterpret_cast<const vf4*>(t) + row0 * F4_PER_ROW;

    vf4 buf0[8], buf1[8];          // 2-row double buffer
    float sums[ROWS_PER_WAVE];

    // ---- READ phase: NT loads (proven best read path, R11 A/B) ----
    #pragma unroll
    for (int j = 0; j < 8; ++j)
        buf0[j] = __builtin_nontemporal_load(base + j * 64 + lane);

    #pragma unroll
    for (int r = 0; r < ROWS_PER_WAVE; ++r) {
        if (r + 1 < ROWS_PER_WAVE) {
            const vf4* p = base + (size_t)(r + 1) * F4_PER_ROW;
            if (r & 1) {
                #pragma unroll
                for (int j = 0; j < 8; ++j)
                    buf0[j] = __builtin_nontemporal_load(p + j * 64 + lane);
            } else {
                #pragma unroll
                for (int j = 0; j < 8; ++j)
                    buf1[j] = __builtin_nontemporal_load(p + j * 64 + lane);
            }
        }

        float s = 0.0f;
        if (r & 1) {
            #pragma unroll
            for (int j = 0; j < 8; ++j)
                s += (buf1[j].x + buf1[j].y) + (buf1[j].z + buf1[j].w);
        } else {
            #pragma unroll
            for (int j = 0; j < 8; ++j)
                s += (buf0[j].x + buf0[j].y) + (buf0[j].z + buf0[j].w);
        }

        // wave-64 butterfly: every lane ends with the full row sum.
        #pragma unroll
        for (int m = 32; m > 0; m >>= 1)
            s += __shfl_xor(s, m, 64);

        sums[r] = scale * s;
    }

    __syncthreads();

    // ---- WRITE phase: PLAIN cached stores (the fill's 6.7 TB/s path) ----
    vf4* obase = reinterpret_cast<vf4*>(out) + row0 * F4_PER_ROW;
    #pragma unroll
    for (int r = 0; r < ROWS_PER_WAVE; ++r) {
        vf4 v4;
        v4.x = sums[r]; v4.y = sums[r]; v4.z = sums[r]; v4.w = sums[r];
        vf4* orow = obase + (size_t)r * F4_PER_ROW;
        #pragma unroll
        for (int j = 0; j < 8; ++j)
            orow[j * 64 + lane] = v4;
    }
}

extern "C" void kernel_launch(void* const* d_in, const int* in_sizes, int n_in,
                              void* d_out, int out_size, void* d_ws, size_t ws_size,
                              hipStream_t stream) {
    const float* t = (const float*)d_in[0];
    const float* w = (const float*)d_in[1];
    float* out = (float*)d_out;
    perm_equiv_ntld_cst<<<GRID_BLOCKS, BLOCK_SIZE, 0, stream>>>(t, w, out);
}